// Round 1
// baseline (530.384 us; speedup 1.0000x reference)
//
#include <hip/hip_runtime.h>
#include <hip/hip_bf16.h>
#include <hip/hip_fp16.h>

// MQA: B=4 H=16 S=2048 DIM=1024 DPH=64. fp16 MFMA path, fp32 accumulate.
// ws layout (bytes):
//   xh    @ 0          16,777,216   [8192][1024] f16
//   wqkvT @ 16777216    2,359,296   [1152][1024] f16  (rows: 0-1023 q(h*64+e), 1024-1087 k, 1088-1151 v)
//   woT   @ 19136512    2,097,152   [1024 d][1024 f] f16
//   qh    @ 21233664   16,777,216   [B][H][S][64] f16
//   kh    @ 38010880    1,048,576   [B][S][64] f16
//   vth   @ 39059456    1,048,576   [B][64][S] f16 (V transposed)
//   oh    @ 40108032   16,777,216   [B][S][1024] f16
//   total 56,885,248

typedef _Float16 f16x8 __attribute__((ext_vector_type(8)));
typedef _Float16 f16x4 __attribute__((ext_vector_type(4)));
typedef float f32x4 __attribute__((ext_vector_type(4)));

#define MFMA16(a, b, c) __builtin_amdgcn_mfma_f32_16x16x32_f16((a), (b), (c), 0, 0, 0)

__device__ __forceinline__ void gll16(const void* g, void* l) {
  __builtin_amdgcn_global_load_lds(
      (__attribute__((address_space(1))) void*)const_cast<void*>(g),
      (__attribute__((address_space(3))) void*)l, 16, 0, 0);
}

__global__ __launch_bounds__(256) void pack_x_kernel(const float* __restrict__ x,
                                                     _Float16* __restrict__ xh) {
  int i = blockIdx.x * 256 + threadIdx.x;  // one thread per 8 elements
  const float4* s = (const float4*)x + (size_t)i * 2;
  float4 a = s[0], b = s[1];
  f16x8 h;
  h[0] = (_Float16)a.x; h[1] = (_Float16)a.y; h[2] = (_Float16)a.z; h[3] = (_Float16)a.w;
  h[4] = (_Float16)b.x; h[5] = (_Float16)b.y; h[6] = (_Float16)b.z; h[7] = (_Float16)b.w;
  ((f16x8*)xh)[i] = h;
}

__global__ __launch_bounds__(256) void pack_w_kernel(
    const float* __restrict__ Wq, const float* __restrict__ Wk,
    const float* __restrict__ Wv, const float* __restrict__ Wo,
    _Float16* __restrict__ wqkvT, _Float16* __restrict__ woT) {
  int i = blockIdx.x * 256 + threadIdx.x;  // 2,228,224 total
  if (i < 1048576) {                    // WqT: row n=(h,e), col d
    int n = i >> 10, d = i & 1023;
    int h = n >> 6, e = n & 63;
    wqkvT[i] = (_Float16)Wq[h * 65536 + d * 64 + e];
  } else if (i < 1114112) {             // WkT
    int j = i - 1048576;
    int e = j >> 10, d = j & 1023;
    wqkvT[i] = (_Float16)Wk[d * 64 + e];
  } else if (i < 1179648) {             // WvT
    int j = i - 1114112;
    int e = j >> 10, d = j & 1023;
    wqkvT[i] = (_Float16)Wv[d * 64 + e];
  } else {                              // WoT[d][f] = Wo[f][d]
    int j = i - 1179648;
    int d = j >> 10, f = j & 1023;
    woT[j] = (_Float16)Wo[f * 1024 + d];
  }
}

// C[m][n] = sum_k A[m][k]*B'[n][k], both row-major over k (NT). Per wave: 16 rows x 64 cols.
__global__ __launch_bounds__(256) void gemm_qkv_kernel(
    const _Float16* __restrict__ xh, const _Float16* __restrict__ wT,
    const float* __restrict__ bq, const float* __restrict__ bk,
    const float* __restrict__ bv,
    _Float16* __restrict__ qh, _Float16* __restrict__ kh,
    _Float16* __restrict__ vth) {
  int lane = threadIdx.x & 63, wave = threadIdx.x >> 6;
  int m0 = blockIdx.x * 64 + wave * 16;
  int n0 = blockIdx.y * 64;
  const _Float16* ap = xh + (size_t)(m0 + (lane & 15)) * 1024 + ((lane >> 4) << 3);
  const _Float16* bp = wT + (size_t)(n0 + (lane & 15)) * 1024 + ((lane >> 4) << 3);
  f32x4 acc[4] = {};
  #pragma unroll 4
  for (int k0 = 0; k0 < 1024; k0 += 32) {
    f16x8 a = *(const f16x8*)(ap + k0);
    #pragma unroll
    for (int nt = 0; nt < 4; nt++) {
      f16x8 bf = *(const f16x8*)(bp + (size_t)nt * 16384 + k0);
      acc[nt] = MFMA16(a, bf, acc[nt]);
    }
  }
  int rbase = m0 + ((lane >> 4) << 2);
  int bb = rbase >> 11;
  int s = rbase & 2047;
  #pragma unroll
  for (int nt = 0; nt < 4; nt++) {
    int n = n0 + nt * 16 + (lane & 15);
    if (n < 1024) {
      float bias = bq[n];
      int h = n >> 6, e = n & 63;
      _Float16* dst = qh + (((size_t)(bb * 16 + h) * 2048 + s) * 64 + e);
      #pragma unroll
      for (int r = 0; r < 4; r++) dst[(size_t)r * 64] = (_Float16)(acc[nt][r] + bias);
    } else if (n < 1088) {
      int e = n - 1024;
      float bias = bk[e];
      _Float16* dst = kh + ((size_t)bb * 2048 + s) * 64 + e;
      #pragma unroll
      for (int r = 0; r < 4; r++) dst[(size_t)r * 64] = (_Float16)(acc[nt][r] + bias);
    } else {
      int e = n - 1088;
      float bias = bv[e];
      f16x4 t;
      #pragma unroll
      for (int r = 0; r < 4; r++) t[r] = (_Float16)(acc[nt][r] + bias);
      *(f16x4*)(vth + ((size_t)bb * 64 + e) * 2048 + s) = t;  // s multiple of 4 -> 8B aligned
    }
  }
}

// Flash attention. Block = 64 q-rows of one (b,h); 4 waves x 16 rows. Full (non-causal) softmax.
// K tile [64 t][64 e] and V tile [64 e][64 t] staged to LDS via global_load_lds(16B) with
// XOR chunk swizzle applied on the GLOBAL source (LDS linear): slot (row,c') holds global
// chunk c'^(row&7); reads use addr = row*128 + ((cwant^(row&7))<<4)  -> 2-way conflicts only.
__global__ __launch_bounds__(256) void attn_kernel(
    const _Float16* __restrict__ qh, const _Float16* __restrict__ kh,
    const _Float16* __restrict__ vth, _Float16* __restrict__ oh) {
  __shared__ __align__(16) _Float16 kbuf[64 * 64];
  __shared__ __align__(16) _Float16 vbuf[64 * 64];
  __shared__ __align__(16) _Float16 pbuf[4][16 * 72];  // per-wave P [16][64], stride 72 (144B, 16B-mult)
  int lane = threadIdx.x & 63, wave = threadIdx.x >> 6;
  int b = blockIdx.z, h = blockIdx.y;
  int q0 = blockIdx.x * 64;

  const _Float16* Qp = qh + (((size_t)(b * 16 + h) * 2048 + q0 + wave * 16 + (lane & 15)) * 64)
                          + ((lane >> 4) << 3);
  f16x8 qf0 = *(const f16x8*)(Qp);
  f16x8 qf1 = *(const f16x8*)(Qp + 32);

  const char* Kb = (const char*)(kh + (size_t)b * 2048 * 64);
  const char* Vb = (const char*)(vth + (size_t)b * 64 * 2048);

  float m_run[4], l_run[4];
  #pragma unroll
  for (int r = 0; r < 4; r++) { m_run[r] = -3.0e38f; l_run[r] = 0.f; }
  f32x4 o_acc[4] = {};

  const int g4 = lane >> 4;  // 0..3
  for (int t0 = 0; t0 < 2048; t0 += 64) {
    const char* ktile = Kb + (size_t)t0 * 128;  // rows contiguous (stride 128B)
    const char* vtile = Vb + (size_t)t0 * 2;    // rows stride 4096B
    #pragma unroll
    for (int i = 0; i < 2; i++) {
      int chunk = wave * 128 + i * 64 + lane;   // 512 chunks of 16B per buffer
      int rr = chunk >> 3, cc = chunk & 7;
      int gc = cc ^ (rr & 7);
      gll16(ktile + (size_t)rr * 128 + gc * 16, (char*)kbuf + chunk * 16);
      gll16(vtile + (size_t)rr * 4096 + gc * 16, (char*)vbuf + chunk * 16);
    }
    __syncthreads();

    // S = Q K^T  (A=Q rows, B'=K rows; contraction over e=64, two k-steps)
    f32x4 sc[4];
    #pragma unroll
    for (int nt = 0; nt < 4; nt++) {
      int row = nt * 16 + (lane & 15);
      const f16x8* k0p = (const f16x8*)((const char*)kbuf + row * 128 + ((g4 ^ (row & 7)) << 4));
      const f16x8* k1p = (const f16x8*)((const char*)kbuf + row * 128 + (((g4 + 4) ^ (row & 7)) << 4));
      f32x4 s4 = {0.f, 0.f, 0.f, 0.f};
      s4 = MFMA16(qf0, *k0p, s4);
      s4 = MFMA16(qf1, *k1p, s4);
      sc[nt] = s4;
    }

    // online softmax; C-layout: col t = nt*16+(lane&15), row = g4*4+r
    float zv[4][4], mt[4];
    #pragma unroll
    for (int r = 0; r < 4; r++) mt[r] = -3.0e38f;
    #pragma unroll
    for (int nt = 0; nt < 4; nt++)
      #pragma unroll
      for (int r = 0; r < 4; r++) {
        zv[nt][r] = sc[nt][r] * 0.125f;
        mt[r] = fmaxf(mt[r], zv[nt][r]);
      }
    #pragma unroll
    for (int mask = 1; mask <= 8; mask <<= 1)
      #pragma unroll
      for (int r = 0; r < 4; r++) mt[r] = fmaxf(mt[r], __shfl_xor(mt[r], mask, 64));
    float al[4], ps[4];
    #pragma unroll
    for (int r = 0; r < 4; r++) {
      float mn = fmaxf(m_run[r], mt[r]);
      al[r] = __expf(m_run[r] - mn);
      m_run[r] = mn;
      ps[r] = 0.f;
    }
    #pragma unroll
    for (int nt = 0; nt < 4; nt++)
      #pragma unroll
      for (int r = 0; r < 4; r++) {
        float p = __expf(zv[nt][r] - m_run[r]);
        ps[r] += p;
        pbuf[wave][((g4 << 2) + r) * 72 + nt * 16 + (lane & 15)] = (_Float16)p;
      }
    #pragma unroll
    for (int mask = 1; mask <= 8; mask <<= 1)
      #pragma unroll
      for (int r = 0; r < 4; r++) ps[r] += __shfl_xor(ps[r], mask, 64);
    f32x4 alv = {al[0], al[1], al[2], al[3]};
    #pragma unroll
    for (int r = 0; r < 4; r++) l_run[r] = l_run[r] * al[r] + ps[r];
    #pragma unroll
    for (int en = 0; en < 4; en++) o_acc[en] *= alv;

    // O += P V  (A=P from LDS, B'=V^T rows from vbuf)
    const f16x8* p0 = (const f16x8*)&pbuf[wave][(lane & 15) * 72 + (g4 << 3)];
    const f16x8* p1 = (const f16x8*)&pbuf[wave][(lane & 15) * 72 + 32 + (g4 << 3)];
    #pragma unroll
    for (int en = 0; en < 4; en++) {
      int e = en * 16 + (lane & 15);
      const f16x8* v0 = (const f16x8*)((const char*)vbuf + e * 128 + ((g4 ^ (e & 7)) << 4));
      const f16x8* v1 = (const f16x8*)((const char*)vbuf + e * 128 + (((g4 + 4) ^ (e & 7)) << 4));
      o_acc[en] = MFMA16(*p0, *v0, o_acc[en]);
      o_acc[en] = MFMA16(*p1, *v1, o_acc[en]);
    }
    __syncthreads();
  }

  // epilogue: oh[b][s][h*64+e]
  int srow = q0 + wave * 16 + (g4 << 2);
  float invl[4];
  #pragma unroll
  for (int r = 0; r < 4; r++) invl[r] = 1.0f / l_run[r];
  #pragma unroll
  for (int en = 0; en < 4; en++) {
    int f = h * 64 + en * 16 + (lane & 15);
    #pragma unroll
    for (int r = 0; r < 4; r++)
      oh[((size_t)b * 2048 + srow + r) * 1024 + f] = (_Float16)(o_acc[en][r] * invl[r]);
  }
}

__global__ __launch_bounds__(256) void gemm_out_kernel(
    const _Float16* __restrict__ oh, const _Float16* __restrict__ woT,
    const float* __restrict__ bo, float* __restrict__ out) {
  int lane = threadIdx.x & 63, wave = threadIdx.x >> 6;
  int m0 = blockIdx.x * 64 + wave * 16;
  int n0 = blockIdx.y * 64;
  const _Float16* ap = oh + (size_t)(m0 + (lane & 15)) * 1024 + ((lane >> 4) << 3);
  const _Float16* bp = woT + (size_t)(n0 + (lane & 15)) * 1024 + ((lane >> 4) << 3);
  f32x4 acc[4] = {};
  #pragma unroll 4
  for (int k0 = 0; k0 < 1024; k0 += 32) {
    f16x8 a = *(const f16x8*)(ap + k0);
    #pragma unroll
    for (int nt = 0; nt < 4; nt++) {
      f16x8 bf = *(const f16x8*)(bp + (size_t)nt * 16384 + k0);
      acc[nt] = MFMA16(a, bf, acc[nt]);
    }
  }
  int rbase = m0 + ((lane >> 4) << 2);
  #pragma unroll
  for (int nt = 0; nt < 4; nt++) {
    int n = n0 + nt * 16 + (lane & 15);
    float bias = bo[n];
    #pragma unroll
    for (int r = 0; r < 4; r++)
      out[(size_t)(rbase + r) * 1024 + n] = acc[nt][r] + bias;
  }
}

extern "C" void kernel_launch(void* const* d_in, const int* in_sizes, int n_in,
                              void* d_out, int out_size, void* d_ws, size_t ws_size,
                              hipStream_t stream) {
  const float* x  = (const float*)d_in[0];
  const float* Wq = (const float*)d_in[1];
  const float* bq = (const float*)d_in[2];
  const float* Wk = (const float*)d_in[3];
  const float* bk = (const float*)d_in[4];
  const float* Wv = (const float*)d_in[5];
  const float* bv = (const float*)d_in[6];
  const float* Wo = (const float*)d_in[7];
  const float* bo = (const float*)d_in[8];
  float* out = (float*)d_out;
  char* ws = (char*)d_ws;

  _Float16* xh   = (_Float16*)(ws);
  _Float16* wqkv = (_Float16*)(ws + 16777216);
  _Float16* woT  = (_Float16*)(ws + 19136512);
  _Float16* qh   = (_Float16*)(ws + 21233664);
  _Float16* kh   = (_Float16*)(ws + 38010880);
  _Float16* vth  = (_Float16*)(ws + 39059456);
  _Float16* oh   = (_Float16*)(ws + 40108032);

  pack_x_kernel<<<4096, 256, 0, stream>>>(x, xh);
  pack_w_kernel<<<8704, 256, 0, stream>>>(Wq, Wk, Wv, Wo, wqkv, woT);
  gemm_qkv_kernel<<<dim3(128, 18), 256, 0, stream>>>(xh, wqkv, bq, bk, bv, qh, kh, vth);
  attn_kernel<<<dim3(32, 16, 4), 256, 0, stream>>>(qh, kh, vth, oh);
  gemm_out_kernel<<<dim3(128, 16), 256, 0, stream>>>(oh, woT, bo, out);
}

// Round 2
// 280.795 us; speedup vs baseline: 1.8889x; 1.8889x over previous
//
#include <hip/hip_runtime.h>
#include <hip/hip_bf16.h>
#include <hip/hip_fp16.h>

// MQA: B=4 H=16 S=2048 DIM=1024 DPH=64. fp16 MFMA path, fp32 accumulate.
// R2: GEMMs rewritten to m97 structure (128x128 tile, LDS staging via
// global_load_lds width-16, BK=32, 2 barriers/K-step). Attention unchanged.
// ws layout (bytes):
//   xh    @ 0          16,777,216   [8192][1024] f16
//   wqkvT @ 16777216    2,359,296   [1152][1024] f16  (rows: 0-1023 q(h*64+e), 1024-1087 k, 1088-1151 v)
//   woT   @ 19136512    2,097,152   [1024 d][1024 f] f16
//   qh    @ 21233664   16,777,216   [B][H][S][64] f16
//   kh    @ 38010880    1,048,576   [B][S][64] f16
//   vth   @ 39059456    1,048,576   [B][64][S] f16 (V transposed)
//   oh    @ 40108032   16,777,216   [B][S][1024] f16
//   total 56,885,248

typedef _Float16 f16x8 __attribute__((ext_vector_type(8)));
typedef _Float16 f16x4 __attribute__((ext_vector_type(4)));
typedef float f32x4 __attribute__((ext_vector_type(4)));

#define MFMA16(a, b, c) __builtin_amdgcn_mfma_f32_16x16x32_f16((a), (b), (c), 0, 0, 0)

__device__ __forceinline__ void gll16(const void* g, void* l) {
  __builtin_amdgcn_global_load_lds(
      (__attribute__((address_space(1))) void*)const_cast<void*>(g),
      (__attribute__((address_space(3))) void*)l, 16, 0, 0);
}

__global__ __launch_bounds__(256) void pack_x_kernel(const float* __restrict__ x,
                                                     _Float16* __restrict__ xh) {
  int i = blockIdx.x * 256 + threadIdx.x;  // one thread per 8 elements
  const float4* s = (const float4*)x + (size_t)i * 2;
  float4 a = s[0], b = s[1];
  f16x8 h;
  h[0] = (_Float16)a.x; h[1] = (_Float16)a.y; h[2] = (_Float16)a.z; h[3] = (_Float16)a.w;
  h[4] = (_Float16)b.x; h[5] = (_Float16)b.y; h[6] = (_Float16)b.z; h[7] = (_Float16)b.w;
  ((f16x8*)xh)[i] = h;
}

__global__ __launch_bounds__(256) void pack_w_kernel(
    const float* __restrict__ Wq, const float* __restrict__ Wk,
    const float* __restrict__ Wv, const float* __restrict__ Wo,
    _Float16* __restrict__ wqkvT, _Float16* __restrict__ woT) {
  int i = blockIdx.x * 256 + threadIdx.x;  // 2,228,224 total
  if (i < 1048576) {                    // WqT: row n=(h,e), col d
    int n = i >> 10, d = i & 1023;
    int h = n >> 6, e = n & 63;
    wqkvT[i] = (_Float16)Wq[h * 65536 + d * 64 + e];
  } else if (i < 1114112) {             // WkT
    int j = i - 1048576;
    int e = j >> 10, d = j & 1023;
    wqkvT[i] = (_Float16)Wk[d * 64 + e];
  } else if (i < 1179648) {             // WvT
    int j = i - 1114112;
    int e = j >> 10, d = j & 1023;
    wqkvT[i] = (_Float16)Wv[d * 64 + e];
  } else {                              // WoT[d][f] = Wo[f][d]
    int j = i - 1179648;
    int d = j >> 10, f = j & 1023;
    woT[j] = (_Float16)Wo[f * 1024 + d];
  }
}

// ---------------- m97-structure GEMM: C[m][n] = sum_k A[m][k] * B'[n][k] ----------------
// 128x128 tile, 4 waves (2x2), BK=32. LDS: A[128][32] + B[128][32] f16 = 16KB, linear
// (row stride 64B -> wave's 8 ds_read_b128 cover contiguous 1KB, conflict-free).
// Staging: 2+2 global_load_lds(16B) per thread per K-step; 2 barriers per K-step.

struct GemmAcc {
  f32x4 acc[4][4];
};

__device__ __forceinline__ void gemm128_core(
    const _Float16* __restrict__ A, const _Float16* __restrict__ Bp,
    int m0, int n0, _Float16* abuf, _Float16* bbuf, GemmAcc& g) {
  const int tid = threadIdx.x;
  const int lane = tid & 63, wave = tid >> 6;
  const int wr = wave >> 1, wc = wave & 1;
  const int g4 = lane >> 4, l15 = lane & 15;

  const char* Ag = (const char*)(A + (size_t)m0 * 1024);
  const char* Bg = (const char*)(Bp + (size_t)n0 * 1024);

  // per-thread staged chunks: c = tid and tid+256; row = c>>2, k-part = (c&3)*8 f16
  const int c0 = tid, c1 = tid + 256;
  const size_t aoff0 = (size_t)(c0 >> 2) * 2048 + (size_t)(c0 & 3) * 16;
  const size_t aoff1 = (size_t)(c1 >> 2) * 2048 + (size_t)(c1 & 3) * 16;
  char* ldsa0 = (char*)abuf + c0 * 16;
  char* ldsa1 = (char*)abuf + c1 * 16;
  char* ldsb0 = (char*)bbuf + c0 * 16;
  char* ldsb1 = (char*)bbuf + c1 * 16;

  // fragment read addresses (loop-invariant)
  const char* ar[4];
  const char* br[4];
  #pragma unroll
  for (int mt = 0; mt < 4; mt++)
    ar[mt] = (const char*)abuf + ((wr << 6) + (mt << 4) + l15) * 64 + (g4 << 4);
  #pragma unroll
  for (int nt = 0; nt < 4; nt++)
    br[nt] = (const char*)bbuf + ((wc << 6) + (nt << 4) + l15) * 64 + (g4 << 4);

  for (int k0 = 0; k0 < 1024; k0 += 32) {
    const size_t kb = (size_t)k0 * 2;
    gll16(Ag + aoff0 + kb, ldsa0);
    gll16(Ag + aoff1 + kb, ldsa1);
    gll16(Bg + aoff0 + kb, ldsb0);
    gll16(Bg + aoff1 + kb, ldsb1);
    __syncthreads();
    f16x8 af[4], bf[4];
    #pragma unroll
    for (int mt = 0; mt < 4; mt++) af[mt] = *(const f16x8*)ar[mt];
    #pragma unroll
    for (int nt = 0; nt < 4; nt++) bf[nt] = *(const f16x8*)br[nt];
    #pragma unroll
    for (int mt = 0; mt < 4; mt++)
      #pragma unroll
      for (int nt = 0; nt < 4; nt++)
        g.acc[mt][nt] = MFMA16(af[mt], bf[nt], g.acc[mt][nt]);
    __syncthreads();
  }
}

__global__ __launch_bounds__(256) void gemm_qkv_kernel(
    const _Float16* __restrict__ xh, const _Float16* __restrict__ wT,
    const float* __restrict__ bq, const float* __restrict__ bk,
    const float* __restrict__ bv,
    _Float16* __restrict__ qh, _Float16* __restrict__ kh,
    _Float16* __restrict__ vth) {
  __shared__ __align__(16) _Float16 abuf[128 * 32];
  __shared__ __align__(16) _Float16 bbuf[128 * 32];
  const int lane = threadIdx.x & 63, wave = threadIdx.x >> 6;
  const int wr = wave >> 1, wc = wave & 1;
  const int g4 = lane >> 4, l15 = lane & 15;
  const int m0 = blockIdx.x * 128;
  const int n0 = blockIdx.y * 128;
  GemmAcc g = {};
  gemm128_core(xh, wT, m0, n0, abuf, bbuf, g);

  #pragma unroll
  for (int mt = 0; mt < 4; mt++) {
    int rbase = m0 + wr * 64 + mt * 16 + (g4 << 2);
    int bb = rbase >> 11;
    int s = rbase & 2047;
    #pragma unroll
    for (int nt = 0; nt < 4; nt++) {
      int n = n0 + wc * 64 + nt * 16 + l15;
      if (n < 1024) {
        float bias = bq[n];
        int h = n >> 6, e = n & 63;
        _Float16* dst = qh + (((size_t)(bb * 16 + h) * 2048 + s) * 64 + e);
        #pragma unroll
        for (int r = 0; r < 4; r++) dst[(size_t)r * 64] = (_Float16)(g.acc[mt][nt][r] + bias);
      } else if (n < 1088) {
        int e = n - 1024;
        float bias = bk[e];
        _Float16* dst = kh + ((size_t)bb * 2048 + s) * 64 + e;
        #pragma unroll
        for (int r = 0; r < 4; r++) dst[(size_t)r * 64] = (_Float16)(g.acc[mt][nt][r] + bias);
      } else {
        int e = n - 1088;
        float bias = bv[e];
        f16x4 t;
        #pragma unroll
        for (int r = 0; r < 4; r++) t[r] = (_Float16)(g.acc[mt][nt][r] + bias);
        *(f16x4*)(vth + ((size_t)bb * 64 + e) * 2048 + s) = t;  // s mult of 4 -> 8B aligned
      }
    }
  }
}

__global__ __launch_bounds__(256) void gemm_out_kernel(
    const _Float16* __restrict__ oh, const _Float16* __restrict__ woT,
    const float* __restrict__ bo, float* __restrict__ out) {
  __shared__ __align__(16) _Float16 abuf[128 * 32];
  __shared__ __align__(16) _Float16 bbuf[128 * 32];
  const int lane = threadIdx.x & 63, wave = threadIdx.x >> 6;
  const int wr = wave >> 1, wc = wave & 1;
  const int g4 = lane >> 4, l15 = lane & 15;
  const int m0 = blockIdx.x * 128;
  const int n0 = blockIdx.y * 128;
  GemmAcc g = {};
  gemm128_core(oh, woT, m0, n0, abuf, bbuf, g);

  #pragma unroll
  for (int mt = 0; mt < 4; mt++) {
    int rbase = m0 + wr * 64 + mt * 16 + (g4 << 2);
    #pragma unroll
    for (int nt = 0; nt < 4; nt++) {
      int n = n0 + wc * 64 + nt * 16 + l15;
      float bias = bo[n];
      #pragma unroll
      for (int r = 0; r < 4; r++)
        out[(size_t)(rbase + r) * 1024 + n] = g.acc[mt][nt][r] + bias;
    }
  }
}

// Flash attention. Block = 64 q-rows of one (b,h); 4 waves x 16 rows. Full (non-causal) softmax.
// K tile [64 t][64 e] and V tile [64 e][64 t] staged to LDS via global_load_lds(16B) with
// XOR chunk swizzle applied on the GLOBAL source (LDS linear): slot (row,c') holds global
// chunk c'^(row&7); reads use addr = row*128 + ((cwant^(row&7))<<4)  -> 2-way conflicts only.
__global__ __launch_bounds__(256) void attn_kernel(
    const _Float16* __restrict__ qh, const _Float16* __restrict__ kh,
    const _Float16* __restrict__ vth, _Float16* __restrict__ oh) {
  __shared__ __align__(16) _Float16 kbuf[64 * 64];
  __shared__ __align__(16) _Float16 vbuf[64 * 64];
  __shared__ __align__(16) _Float16 pbuf[4][16 * 72];  // per-wave P [16][64], stride 72 (144B, 16B-mult)
  int lane = threadIdx.x & 63, wave = threadIdx.x >> 6;
  int b = blockIdx.z, h = blockIdx.y;
  int q0 = blockIdx.x * 64;

  const _Float16* Qp = qh + (((size_t)(b * 16 + h) * 2048 + q0 + wave * 16 + (lane & 15)) * 64)
                          + ((lane >> 4) << 3);
  f16x8 qf0 = *(const f16x8*)(Qp);
  f16x8 qf1 = *(const f16x8*)(Qp + 32);

  const char* Kb = (const char*)(kh + (size_t)b * 2048 * 64);
  const char* Vb = (const char*)(vth + (size_t)b * 64 * 2048);

  float m_run[4], l_run[4];
  #pragma unroll
  for (int r = 0; r < 4; r++) { m_run[r] = -3.0e38f; l_run[r] = 0.f; }
  f32x4 o_acc[4] = {};

  const int g4 = lane >> 4;  // 0..3
  for (int t0 = 0; t0 < 2048; t0 += 64) {
    const char* ktile = Kb + (size_t)t0 * 128;  // rows contiguous (stride 128B)
    const char* vtile = Vb + (size_t)t0 * 2;    // rows stride 4096B
    #pragma unroll
    for (int i = 0; i < 2; i++) {
      int chunk = wave * 128 + i * 64 + lane;   // 512 chunks of 16B per buffer
      int rr = chunk >> 3, cc = chunk & 7;
      int gc = cc ^ (rr & 7);
      gll16(ktile + (size_t)rr * 128 + gc * 16, (char*)kbuf + chunk * 16);
      gll16(vtile + (size_t)rr * 4096 + gc * 16, (char*)vbuf + chunk * 16);
    }
    __syncthreads();

    // S = Q K^T  (A=Q rows, B'=K rows; contraction over e=64, two k-steps)
    f32x4 sc[4];
    #pragma unroll
    for (int nt = 0; nt < 4; nt++) {
      int row = nt * 16 + (lane & 15);
      const f16x8* k0p = (const f16x8*)((const char*)kbuf + row * 128 + ((g4 ^ (row & 7)) << 4));
      const f16x8* k1p = (const f16x8*)((const char*)kbuf + row * 128 + (((g4 + 4) ^ (row & 7)) << 4));
      f32x4 s4 = {0.f, 0.f, 0.f, 0.f};
      s4 = MFMA16(qf0, *k0p, s4);
      s4 = MFMA16(qf1, *k1p, s4);
      sc[nt] = s4;
    }

    // online softmax; C-layout: col t = nt*16+(lane&15), row = g4*4+r
    float zv[4][4], mt[4];
    #pragma unroll
    for (int r = 0; r < 4; r++) mt[r] = -3.0e38f;
    #pragma unroll
    for (int nt = 0; nt < 4; nt++)
      #pragma unroll
      for (int r = 0; r < 4; r++) {
        zv[nt][r] = sc[nt][r] * 0.125f;
        mt[r] = fmaxf(mt[r], zv[nt][r]);
      }
    #pragma unroll
    for (int mask = 1; mask <= 8; mask <<= 1)
      #pragma unroll
      for (int r = 0; r < 4; r++) mt[r] = fmaxf(mt[r], __shfl_xor(mt[r], mask, 64));
    float al[4], ps[4];
    #pragma unroll
    for (int r = 0; r < 4; r++) {
      float mn = fmaxf(m_run[r], mt[r]);
      al[r] = __expf(m_run[r] - mn);
      m_run[r] = mn;
      ps[r] = 0.f;
    }
    #pragma unroll
    for (int nt = 0; nt < 4; nt++)
      #pragma unroll
      for (int r = 0; r < 4; r++) {
        float p = __expf(zv[nt][r] - m_run[r]);
        ps[r] += p;
        pbuf[wave][((g4 << 2) + r) * 72 + nt * 16 + (lane & 15)] = (_Float16)p;
      }
    #pragma unroll
    for (int mask = 1; mask <= 8; mask <<= 1)
      #pragma unroll
      for (int r = 0; r < 4; r++) ps[r] += __shfl_xor(ps[r], mask, 64);
    f32x4 alv = {al[0], al[1], al[2], al[3]};
    #pragma unroll
    for (int r = 0; r < 4; r++) l_run[r] = l_run[r] * al[r] + ps[r];
    #pragma unroll
    for (int en = 0; en < 4; en++) o_acc[en] *= alv;

    // O += P V  (A=P from LDS, B'=V^T rows from vbuf)
    const f16x8* p0 = (const f16x8*)&pbuf[wave][(lane & 15) * 72 + (g4 << 3)];
    const f16x8* p1 = (const f16x8*)&pbuf[wave][(lane & 15) * 72 + 32 + (g4 << 3)];
    #pragma unroll
    for (int en = 0; en < 4; en++) {
      int e = en * 16 + (lane & 15);
      const f16x8* v0 = (const f16x8*)((const char*)vbuf + e * 128 + ((g4 ^ (e & 7)) << 4));
      const f16x8* v1 = (const f16x8*)((const char*)vbuf + e * 128 + (((g4 + 4) ^ (e & 7)) << 4));
      o_acc[en] = MFMA16(*p0, *v0, o_acc[en]);
      o_acc[en] = MFMA16(*p1, *v1, o_acc[en]);
    }
    __syncthreads();
  }

  // epilogue: oh[b][s][h*64+e]
  int srow = q0 + wave * 16 + (g4 << 2);
  float invl[4];
  #pragma unroll
  for (int r = 0; r < 4; r++) invl[r] = 1.0f / l_run[r];
  #pragma unroll
  for (int en = 0; en < 4; en++) {
    int f = h * 64 + en * 16 + (lane & 15);
    #pragma unroll
    for (int r = 0; r < 4; r++)
      oh[((size_t)b * 2048 + srow + r) * 1024 + f] = (_Float16)(o_acc[en][r] * invl[r]);
  }
}

extern "C" void kernel_launch(void* const* d_in, const int* in_sizes, int n_in,
                              void* d_out, int out_size, void* d_ws, size_t ws_size,
                              hipStream_t stream) {
  const float* x  = (const float*)d_in[0];
  const float* Wq = (const float*)d_in[1];
  const float* bq = (const float*)d_in[2];
  const float* Wk = (const float*)d_in[3];
  const float* bk = (const float*)d_in[4];
  const float* Wv = (const float*)d_in[5];
  const float* bv = (const float*)d_in[6];
  const float* Wo = (const float*)d_in[7];
  const float* bo = (const float*)d_in[8];
  float* out = (float*)d_out;
  char* ws = (char*)d_ws;

  _Float16* xh   = (_Float16*)(ws);
  _Float16* wqkv = (_Float16*)(ws + 16777216);
  _Float16* woT  = (_Float16*)(ws + 19136512);
  _Float16* qh   = (_Float16*)(ws + 21233664);
  _Float16* kh   = (_Float16*)(ws + 38010880);
  _Float16* vth  = (_Float16*)(ws + 39059456);
  _Float16* oh   = (_Float16*)(ws + 40108032);

  pack_x_kernel<<<4096, 256, 0, stream>>>(x, xh);
  pack_w_kernel<<<8704, 256, 0, stream>>>(Wq, Wk, Wv, Wo, wqkv, woT);
  gemm_qkv_kernel<<<dim3(64, 9), 256, 0, stream>>>(xh, wqkv, bq, bk, bv, qh, kh, vth);
  attn_kernel<<<dim3(32, 16, 4), 256, 0, stream>>>(qh, kh, vth, oh);
  gemm_out_kernel<<<dim3(64, 8), 256, 0, stream>>>(oh, woT, bo, out);
}

// Round 3
// 204.012 us; speedup vs baseline: 2.5998x; 1.3764x over previous
//
#include <hip/hip_runtime.h>
#include <hip/hip_bf16.h>
#include <hip/hip_fp16.h>

// MQA: B=4 H=16 S=2048 DIM=1024 DPH=64. fp16 MFMA path, fp32 accumulate.
// R3: attention rewritten to swapped-operand 32x32x16 structure:
//   S^T = K.Q^T  (lane owns one q-row), K rows bit-permuted in LDS so the
//   QK^T C-layout feeds PV's B-fragment directly (zero cross-lane P moves).
//   log2-domain softmax (Q pre-scaled by 0.125*log2e in GEMM epilogue),
//   defer-max THR=8, double-buffered K/V with 2-phase prefetch.
// ws layout (bytes):
//   xh    @ 0          16,777,216   [8192][1024] f16
//   wqkvT @ 16777216    2,359,296   [1152][1024] f16
//   woT   @ 19136512    2,097,152   [1024 d][1024 f] f16
//   qh    @ 21233664   16,777,216   [B][H][S][64] f16 (PRE-SCALED by 0.1803369)
//   kh    @ 38010880    1,048,576   [B][S][64] f16
//   vth   @ 39059456    1,048,576   [B][64][S] f16 (V transposed)
//   oh    @ 40108032   16,777,216   [B][S][1024] f16

typedef _Float16 f16x8 __attribute__((ext_vector_type(8)));
typedef _Float16 f16x4 __attribute__((ext_vector_type(4)));
typedef float f32x4 __attribute__((ext_vector_type(4)));
typedef float f32x16 __attribute__((ext_vector_type(16)));

#define MFMA16(a, b, c) __builtin_amdgcn_mfma_f32_16x16x32_f16((a), (b), (c), 0, 0, 0)
#define MFMA32(a, b, c) __builtin_amdgcn_mfma_f32_32x32x16_f16((a), (b), (c), 0, 0, 0)

__device__ __forceinline__ void gll16(const void* g, void* l) {
  __builtin_amdgcn_global_load_lds(
      (__attribute__((address_space(1))) void*)const_cast<void*>(g),
      (__attribute__((address_space(3))) void*)l, 16, 0, 0);
}

__global__ __launch_bounds__(256) void pack_x_kernel(const float* __restrict__ x,
                                                     _Float16* __restrict__ xh) {
  int i = blockIdx.x * 256 + threadIdx.x;
  const float4* s = (const float4*)x + (size_t)i * 2;
  float4 a = s[0], b = s[1];
  f16x8 h;
  h[0] = (_Float16)a.x; h[1] = (_Float16)a.y; h[2] = (_Float16)a.z; h[3] = (_Float16)a.w;
  h[4] = (_Float16)b.x; h[5] = (_Float16)b.y; h[6] = (_Float16)b.z; h[7] = (_Float16)b.w;
  ((f16x8*)xh)[i] = h;
}

__global__ __launch_bounds__(256) void pack_w_kernel(
    const float* __restrict__ Wq, const float* __restrict__ Wk,
    const float* __restrict__ Wv, const float* __restrict__ Wo,
    _Float16* __restrict__ wqkvT, _Float16* __restrict__ woT) {
  int i = blockIdx.x * 256 + threadIdx.x;
  if (i < 1048576) {
    int n = i >> 10, d = i & 1023;
    int h = n >> 6, e = n & 63;
    wqkvT[i] = (_Float16)Wq[h * 65536 + d * 64 + e];
  } else if (i < 1114112) {
    int j = i - 1048576;
    int e = j >> 10, d = j & 1023;
    wqkvT[i] = (_Float16)Wk[d * 64 + e];
  } else if (i < 1179648) {
    int j = i - 1114112;
    int e = j >> 10, d = j & 1023;
    wqkvT[i] = (_Float16)Wv[d * 64 + e];
  } else {
    int j = i - 1179648;
    int d = j >> 10, f = j & 1023;
    woT[j] = (_Float16)Wo[f * 1024 + d];
  }
}

// ---------------- m97-structure GEMM (unchanged from R2) ----------------
struct GemmAcc {
  f32x4 acc[4][4];
};

__device__ __forceinline__ void gemm128_core(
    const _Float16* __restrict__ A, const _Float16* __restrict__ Bp,
    int m0, int n0, _Float16* abuf, _Float16* bbuf, GemmAcc& g) {
  const int tid = threadIdx.x;
  const int lane = tid & 63, wave = tid >> 6;
  const int wr = wave >> 1, wc = wave & 1;
  const int g4 = lane >> 4, l15 = lane & 15;

  const char* Ag = (const char*)(A + (size_t)m0 * 1024);
  const char* Bg = (const char*)(Bp + (size_t)n0 * 1024);

  const int c0 = tid, c1 = tid + 256;
  const size_t aoff0 = (size_t)(c0 >> 2) * 2048 + (size_t)(c0 & 3) * 16;
  const size_t aoff1 = (size_t)(c1 >> 2) * 2048 + (size_t)(c1 & 3) * 16;
  char* ldsa0 = (char*)abuf + c0 * 16;
  char* ldsa1 = (char*)abuf + c1 * 16;
  char* ldsb0 = (char*)bbuf + c0 * 16;
  char* ldsb1 = (char*)bbuf + c1 * 16;

  const char* ar[4];
  const char* br[4];
  #pragma unroll
  for (int mt = 0; mt < 4; mt++)
    ar[mt] = (const char*)abuf + ((wr << 6) + (mt << 4) + l15) * 64 + (g4 << 4);
  #pragma unroll
  for (int nt = 0; nt < 4; nt++)
    br[nt] = (const char*)bbuf + ((wc << 6) + (nt << 4) + l15) * 64 + (g4 << 4);

  for (int k0 = 0; k0 < 1024; k0 += 32) {
    const size_t kb = (size_t)k0 * 2;
    gll16(Ag + aoff0 + kb, ldsa0);
    gll16(Ag + aoff1 + kb, ldsa1);
    gll16(Bg + aoff0 + kb, ldsb0);
    gll16(Bg + aoff1 + kb, ldsb1);
    __syncthreads();
    f16x8 af[4], bf[4];
    #pragma unroll
    for (int mt = 0; mt < 4; mt++) af[mt] = *(const f16x8*)ar[mt];
    #pragma unroll
    for (int nt = 0; nt < 4; nt++) bf[nt] = *(const f16x8*)br[nt];
    #pragma unroll
    for (int mt = 0; mt < 4; mt++)
      #pragma unroll
      for (int nt = 0; nt < 4; nt++)
        g.acc[mt][nt] = MFMA16(af[mt], bf[nt], g.acc[mt][nt]);
    __syncthreads();
  }
}

__global__ __launch_bounds__(256) void gemm_qkv_kernel(
    const _Float16* __restrict__ xh, const _Float16* __restrict__ wT,
    const float* __restrict__ bq, const float* __restrict__ bk,
    const float* __restrict__ bv,
    _Float16* __restrict__ qh, _Float16* __restrict__ kh,
    _Float16* __restrict__ vth) {
  __shared__ __align__(16) _Float16 abuf[128 * 32];
  __shared__ __align__(16) _Float16 bbuf[128 * 32];
  const int lane = threadIdx.x & 63, wave = threadIdx.x >> 6;
  const int wr = wave >> 1, wc = wave & 1;
  const int g4 = lane >> 4, l15 = lane & 15;
  const int m0 = blockIdx.x * 128;
  const int n0 = blockIdx.y * 128;
  GemmAcc g = {};
  gemm128_core(xh, wT, m0, n0, abuf, bbuf, g);

  // q outputs pre-scaled by softmax_scale * log2(e) so attention runs in log2 domain
  const float QSCALE = 0.18033688011112042f;  // 0.125 * log2(e)
  #pragma unroll
  for (int mt = 0; mt < 4; mt++) {
    int rbase = m0 + wr * 64 + mt * 16 + (g4 << 2);
    int bb = rbase >> 11;
    int s = rbase & 2047;
    #pragma unroll
    for (int nt = 0; nt < 4; nt++) {
      int n = n0 + wc * 64 + nt * 16 + l15;
      if (n < 1024) {
        float bias = bq[n];
        int h = n >> 6, e = n & 63;
        _Float16* dst = qh + (((size_t)(bb * 16 + h) * 2048 + s) * 64 + e);
        #pragma unroll
        for (int r = 0; r < 4; r++)
          dst[(size_t)r * 64] = (_Float16)((g.acc[mt][nt][r] + bias) * QSCALE);
      } else if (n < 1088) {
        int e = n - 1024;
        float bias = bk[e];
        _Float16* dst = kh + ((size_t)bb * 2048 + s) * 64 + e;
        #pragma unroll
        for (int r = 0; r < 4; r++) dst[(size_t)r * 64] = (_Float16)(g.acc[mt][nt][r] + bias);
      } else {
        int e = n - 1088;
        float bias = bv[e];
        f16x4 t;
        #pragma unroll
        for (int r = 0; r < 4; r++) t[r] = (_Float16)(g.acc[mt][nt][r] + bias);
        *(f16x4*)(vth + ((size_t)bb * 64 + e) * 2048 + s) = t;
      }
    }
  }
}

__global__ __launch_bounds__(256) void gemm_out_kernel(
    const _Float16* __restrict__ oh, const _Float16* __restrict__ woT,
    const float* __restrict__ bo, float* __restrict__ out) {
  __shared__ __align__(16) _Float16 abuf[128 * 32];
  __shared__ __align__(16) _Float16 bbuf[128 * 32];
  const int lane = threadIdx.x & 63, wave = threadIdx.x >> 6;
  const int wr = wave >> 1, wc = wave & 1;
  const int g4 = lane >> 4, l15 = lane & 15;
  const int m0 = blockIdx.x * 128;
  const int n0 = blockIdx.y * 128;
  GemmAcc g = {};
  gemm128_core(oh, woT, m0, n0, abuf, bbuf, g);

  #pragma unroll
  for (int mt = 0; mt < 4; mt++) {
    int rbase = m0 + wr * 64 + mt * 16 + (g4 << 2);
    #pragma unroll
    for (int nt = 0; nt < 4; nt++) {
      int n = n0 + wc * 64 + nt * 16 + l15;
      float bias = bo[n];
      #pragma unroll
      for (int r = 0; r < 4; r++)
        out[(size_t)(rbase + r) * 1024 + n] = g.acc[mt][nt][r] + bias;
    }
  }
}

// ---------------- Flash attention, swapped-operand 32x32x16 ----------------
// Block: 128 q-rows of one (b,h); 4 waves x 32 q-rows. KV tile = 64, dbl-buffered.
// LDS (32KB): kbuf[2][64 rows][64 d] + vbuf[2][64 e][64 t], 16B-chunk XOR swizzle
// (chunk ^= row&7) with swizzle pre-applied on the GLOBAL source (LDS stays linear
// for global_load_lds). K rows additionally bit-permuted: LDS row m holds global
// K row t = perm(m), perm = swap bits 2<->3. Then QK^T C-reg r of k-tile mt maps to
// global t = mt*32 + r[3]*16 + h*8 + r[2:0]  (h = lane>>5), so PV's B-frag for
// k-step s is acc[s>>1] regs [(s&1)*8 .. +7] -- consecutive, no cross-lane moves.
__global__ __launch_bounds__(256) void attn_kernel(
    const _Float16* __restrict__ qh, const _Float16* __restrict__ kh,
    const _Float16* __restrict__ vth, _Float16* __restrict__ oh) {
  __shared__ __align__(16) _Float16 smem[16384];  // 32KB: K[2][4096] | V[2][4096]
  const int tid = threadIdx.x;
  const int lane = tid & 63, wave = tid >> 6;
  const int l31 = lane & 31, h = lane >> 5;
  const int b = blockIdx.z, hd = blockIdx.y;
  const int q0 = blockIdx.x * 128;

  // Q fragments: B-operand, col = l31 (q-row), k-slice d = s*16 + h*8 .. +7
  const _Float16* Qrow = qh + (((size_t)(b * 16 + hd) * 2048 + q0 + wave * 32 + l31) * 64);
  f16x8 qf[4];
  #pragma unroll
  for (int s = 0; s < 4; s++) qf[s] = *(const f16x8*)(Qrow + s * 16 + h * 8);

  const char* Kb = (const char*)(kh + (size_t)b * 2048 * 64);
  const char* Vb = (const char*)(vth + (size_t)b * 64 * 2048);

  // staging descriptors: thread handles chunks {tid, tid+256} of K and of V
  const char* srcK[2];
  const char* srcV[2];
  int dsto[2];
  #pragma unroll
  for (int i = 0; i < 2; i++) {
    int c = tid + i * 256;
    int m = c >> 3, c8 = c & 7;
    int gc = c8 ^ (m & 7);
    int tsrc = (m & 51) | ((m & 4) << 1) | ((m & 8) >> 1);  // swap bits 2,3
    srcK[i] = Kb + (size_t)tsrc * 128 + gc * 16;
    srcV[i] = Vb + (size_t)m * 4096 + gc * 16;  // V rows = e, no perm
    dsto[i] = c * 16;
  }

  float m_run = -1.0e30f, l_run = 0.f;
  f32x16 oa0 = {}, oa1 = {};

  // prologue: stage tile 0 into buf 0
  {
    char* kb = (char*)smem;
    char* vb = (char*)smem + 16384;
    #pragma unroll
    for (int i = 0; i < 2; i++) {
      gll16(srcK[i], kb + dsto[i]);
      gll16(srcV[i], vb + dsto[i]);
    }
  }
  __syncthreads();

  const int rowK0 = l31 * 128, rowK1 = (l31 + 32) * 128;
  const int swz = (l31 & 7);  // same key for row and row+32

  for (int it = 0; it < 32; ++it) {
    const int cur = it & 1;
    const char* kb = (const char*)smem + cur * 8192;
    const char* vb = (const char*)smem + 16384 + cur * 8192;

    // prefetch next tile into other buffer (overlaps with compute below)
    if (it + 1 < 32) {
      char* kbn = (char*)smem + (cur ^ 1) * 8192;
      char* vbn = (char*)smem + 16384 + (cur ^ 1) * 8192;
      const size_t koff = (size_t)(it + 1) * 8192;  // 64 rows * 128B
      const size_t voff = (size_t)(it + 1) * 128;   // 64 t * 2B
      #pragma unroll
      for (int i = 0; i < 2; i++) {
        gll16(srcK[i] + koff, kbn + dsto[i]);
        gll16(srcV[i] + voff, vbn + dsto[i]);
      }
    }

    // ---- S^T = K . Q^T : acc0 = LDS k-rows 0..31, acc1 = rows 32..63 ----
    f32x16 s0 = {}, s1 = {};
    #pragma unroll
    for (int s = 0; s < 4; s++) {
      const int ch = ((2 * s + h) ^ swz) << 4;
      f16x8 a0 = *(const f16x8*)(kb + rowK0 + ch);
      f16x8 a1 = *(const f16x8*)(kb + rowK1 + ch);
      s0 = MFMA32(a0, qf[s], s0);
      s1 = MFMA32(a1, qf[s], s1);
    }

    // ---- online softmax (log2 domain; lane owns q-row l31; partner = lane^32) ----
    float vm[8];
    #pragma unroll
    for (int i = 0; i < 8; i++)
      vm[i] = fmaxf(fmaxf(s0[i], s0[i + 8]), fmaxf(s1[i], s1[i + 8]));
    float pm = fmaxf(fmaxf(fmaxf(vm[0], vm[1]), fmaxf(vm[2], vm[3])),
                     fmaxf(fmaxf(vm[4], vm[5]), fmaxf(vm[6], vm[7])));
    pm = fmaxf(pm, __shfl_xor(pm, 32));

    if (__any(pm > m_run + 8.0f)) {  // defer-max, THR=8 (log2 units)
      float mnew = fmaxf(m_run, pm);
      float al = exp2f(m_run - mnew);
      m_run = mnew;
      l_run *= al;
      #pragma unroll
      for (int i = 0; i < 16; i++) { oa0[i] *= al; oa1[i] *= al; }
    }

    #pragma unroll
    for (int i = 0; i < 16; i++) {
      s0[i] = exp2f(s0[i] - m_run);
      s1[i] = exp2f(s1[i] - m_run);
    }
    // sum tree
    float sm[8];
    #pragma unroll
    for (int i = 0; i < 8; i++) sm[i] = (s0[i] + s0[i + 8]) + (s1[i] + s1[i + 8]);
    float ps = ((sm[0] + sm[1]) + (sm[2] + sm[3])) + ((sm[4] + sm[5]) + (sm[6] + sm[7]));
    ps += __shfl_xor(ps, 32);
    l_run += ps;

    // ---- pack P to f16 B-frags: pf[s] = acc[s>>1] regs [(s&1)*8 .. +7] ----
    f16x8 pf[4];
    #pragma unroll
    for (int s = 0; s < 4; s++) {
      #pragma unroll
      for (int j = 0; j < 8; j++)
        pf[s][j] = (_Float16)((s < 2 ? s0 : s1)[(s & 1) * 8 + j]);
    }

    // ---- O^T += V^T . P^T : A = vbuf rows e, B = pf ----
    #pragma unroll
    for (int s = 0; s < 4; s++) {
      const int ch = ((2 * s + h) ^ swz) << 4;
      f16x8 a0 = *(const f16x8*)(vb + rowK0 + ch);
      f16x8 a1 = *(const f16x8*)(vb + rowK1 + ch);
      oa0 = MFMA32(a0, pf[s], oa0);
      oa1 = MFMA32(a1, pf[s], oa1);
    }

    __syncthreads();  // drains vmcnt -> next tile staged; buffers safe to flip
  }

  // ---- epilogue: de-transpose O^T via LDS, divide by l, store coalesced ----
  // lane holds q = l31, e = et*32 + (r&3) + 8*(r>>2) + 4h
  _Float16* ob = smem + wave * 2048;  // [32 q][64 e] per wave (reuses K buffers)
  float invl = 1.0f / l_run;
  #pragma unroll
  for (int rh = 0; rh < 4; rh++) {
    f16x4 t0, t1;
    #pragma unroll
    for (int j = 0; j < 4; j++) {
      t0[j] = (_Float16)(oa0[rh * 4 + j] * invl);
      t1[j] = (_Float16)(oa1[rh * 4 + j] * invl);
    }
    *(f16x4*)&ob[l31 * 64 + rh * 8 + h * 4] = t0;
    *(f16x4*)&ob[l31 * 64 + 32 + rh * 8 + h * 4] = t1;
  }
  // same-wave read-after-write: compiler inserts lgkmcnt wait; no barrier needed
  const int q_ = lane >> 1, hf = lane & 1;
  const size_t orow = ((size_t)b * 2048 + q0 + wave * 32 + q_) * 1024 + hd * 64 + hf * 32;
  #pragma unroll
  for (int c = 0; c < 4; c++) {
    f16x8 v = *(const f16x8*)&ob[q_ * 64 + hf * 32 + c * 8];
    *(f16x8*)(oh + orow + c * 8) = v;
  }
}

extern "C" void kernel_launch(void* const* d_in, const int* in_sizes, int n_in,
                              void* d_out, int out_size, void* d_ws, size_t ws_size,
                              hipStream_t stream) {
  const float* x  = (const float*)d_in[0];
  const float* Wq = (const float*)d_in[1];
  const float* bq = (const float*)d_in[2];
  const float* Wk = (const float*)d_in[3];
  const float* bk = (const float*)d_in[4];
  const float* Wv = (const float*)d_in[5];
  const float* bv = (const float*)d_in[6];
  const float* Wo = (const float*)d_in[7];
  const float* bo = (const float*)d_in[8];
  float* out = (float*)d_out;
  char* ws = (char*)d_ws;

  _Float16* xh   = (_Float16*)(ws);
  _Float16* wqkv = (_Float16*)(ws + 16777216);
  _Float16* woT  = (_Float16*)(ws + 19136512);
  _Float16* qh   = (_Float16*)(ws + 21233664);
  _Float16* kh   = (_Float16*)(ws + 38010880);
  _Float16* vth  = (_Float16*)(ws + 39059456);
  _Float16* oh   = (_Float16*)(ws + 40108032);

  pack_x_kernel<<<4096, 256, 0, stream>>>(x, xh);
  pack_w_kernel<<<8704, 256, 0, stream>>>(Wq, Wk, Wv, Wo, wqkv, woT);
  gemm_qkv_kernel<<<dim3(64, 9), 256, 0, stream>>>(xh, wqkv, bq, bk, bv, qh, kh, vth);
  attn_kernel<<<dim3(16, 16, 4), 256, 0, stream>>>(qh, kh, vth, oh);
  gemm_out_kernel<<<dim3(64, 8), 256, 0, stream>>>(oh, woT, bo, out);
}